// Round 8
// baseline (598.458 us; speedup 1.0000x reference)
//
#include <hip/hip_runtime.h>
#include <math.h>

#define HID 128
#define NG_GAUSS 50
#define TBL_P 8192
#define TBL_DMAX 12.8f
#define TBL_DT (TBL_DMAX / (float)TBL_P)
#define TBL_INV_DT ((float)TBL_P / TBL_DMAX)
#define PI_F 3.14159265358979323846f

typedef short bf16x8 __attribute__((ext_vector_type(8)));
typedef float f32x4 __attribute__((ext_vector_type(4)));

__device__ __forceinline__ float ssp_f(float x) {
  float e = __expf(-fabsf(x));
  return fmaxf(x, 0.f) + __logf(1.f + e) - 0.69314718055994530942f;
}
__device__ __forceinline__ unsigned short f2bf(float x) {
  unsigned u = __float_as_uint(x);
  unsigned r = (u + 0x7FFFu + ((u >> 16) & 1u)) >> 16;
  return (unsigned short)r;
}
__device__ __forceinline__ float bf2f_s(unsigned short v) {
  return __uint_as_float((unsigned)v << 16);
}

// ---------------- edge precompute: pack (row<<13 | i0), cull zero edges ---
__global__ __launch_bounds__(256) void k_edge_pre(
    const float* __restrict__ pos, const int* __restrict__ ei,
    int E, int* __restrict__ epack, int* __restrict__ deg)
{
  int e = blockIdx.x * 256 + threadIdx.x;
  if (e >= E) return;
  int r = ei[e];
  int c = ei[E + e];
  float dx = pos[3*r+0] - pos[3*c+0];
  float dy = pos[3*r+1] - pos[3*c+1];
  float dz = pos[3*r+2] - pos[3*c+2];
  float d = sqrtf(dx*dx + dy*dy + dz*dz);
  int i0 = (int)(d * TBL_INV_DT + 0.5f);
  if (i0 >= TBL_P) { epack[e] = -1; return; }  // d>=12.8: gaussians underflow,
                                               // zero biases => filter exactly 0
  epack[e] = (r << 13) | i0;
  atomicAdd(&deg[c], 1);
}

// ---------------- exclusive scan over degrees (single block, 2-level) -----
__global__ __launch_bounds__(1024) void k_scan(
    const int* __restrict__ deg, int* __restrict__ ptr, int N)
{
  __shared__ int wsum[16];
  int t = threadIdx.x;
  int chunk = (N + 1023) / 1024;
  int b = t * chunk;
  int e2 = min(b + chunk, N);
  int s = 0;
  for (int i = b; i < e2; ++i) s += deg[i];
  int lane = t & 63, w = t >> 6;
  int ps = s;
  for (int o = 1; o < 64; o <<= 1) { int x = __shfl_up(ps, o); if (lane >= o) ps += x; }
  if (lane == 63) wsum[w] = ps;
  __syncthreads();
  if (w == 0 && lane < 16) {
    int v = wsum[lane];
    int pv = v;
    for (int o = 1; o < 16; o <<= 1) { int x = __shfl_up(pv, o); if (lane >= o) pv += x; }
    wsum[lane] = pv - v;  // exclusive
  }
  __syncthreads();
  int base = wsum[w] + ps - s;
  for (int i = b; i < e2; ++i) { ptr[i] = base; base += deg[i]; }
  if (t == 1023) ptr[N] = base;
}

// ---------------- scatter edges into CSR order (skip culled) --------------
__global__ __launch_bounds__(256) void k_csr_scatter(
    const int* __restrict__ col, const int* __restrict__ epack,
    const int* __restrict__ ptr, int* __restrict__ cursor,
    int* __restrict__ csr, int E)
{
  int e = blockIdx.x * 256 + threadIdx.x;
  if (e >= E) return;
  int p = epack[e];
  if (p < 0) return;
  int c = col[e];
  int slot = ptr[c] + atomicAdd(&cursor[c], 1);
  csr[slot] = p;
}

// ---------------- weight prep: bf16, transposed [n][k], chunk-XOR swizzle -
// grid (L, 6 types, 2 k-halves)
__global__ __launch_bounds__(256) void k_wprep(
    const float* __restrict__ aw_w, const float* __restrict__ out_w1,
    const float* __restrict__ out_w2, const float* __restrict__ mlp_w2,
    const float* __restrict__ mlp_w1, const float* __restrict__ head_w1,
    unsigned short* __restrict__ awt, unsigned short* __restrict__ o1t,
    unsigned short* __restrict__ o2t, unsigned short* __restrict__ m2t,
    unsigned short* __restrict__ m1t, unsigned short* __restrict__ hwt)
{
  __shared__ float Wl[64][132];
  int l = blockIdx.x, t = blockIdx.y;
  int k0 = blockIdx.z * 64;
  const float* src; unsigned short* dst; int K; int NCOL = 128;
  switch (t) {
    case 0:  src = aw_w;   dst = awt; K = 128; break;
    case 1:  src = out_w1; dst = o1t; K = 128; break;
    case 2:  src = out_w2; dst = o2t; K = 128; break;
    case 3:  src = mlp_w2; dst = m2t; K = 128; break;
    case 4:  src = mlp_w1; dst = m1t; K = NG_GAUSS; break;
    default:
      if (l) return;
      src = head_w1; dst = hwt; K = 128; NCOL = 64; break;
  }
  src += (long)l * K * NCOL;
  dst += (long)l * 128 * 128;
  const int tid = threadIdx.x;
  for (int idx = tid; idx < 64 * 128; idx += 256) {
    int kk = idx >> 7, n = idx & 127;
    int k = k0 + kk;
    Wl[kk][n] = (k < K && n < NCOL) ? src[(long)k * NCOL + n] : 0.f;
  }
  __syncthreads();
  for (int idx = tid; idx < 128 * 8; idx += 256) {
    int n = idx >> 3, pl = idx & 7;
    int p = (k0 >> 3) + pl;            // stored chunk position
    int q = p ^ (n & 7);               // logical chunk (same 8-chunk half)
    int kk = (q << 3) - k0;
    ushort4 lo = make_ushort4(f2bf(Wl[kk+0][n]), f2bf(Wl[kk+1][n]),
                              f2bf(Wl[kk+2][n]), f2bf(Wl[kk+3][n]));
    ushort4 hi = make_ushort4(f2bf(Wl[kk+4][n]), f2bf(Wl[kk+5][n]),
                              f2bf(Wl[kk+6][n]), f2bf(Wl[kk+7][n]));
    *(ushort4*)(dst + ((long)n << 7) + (p << 3)) = lo;
    *(ushort4*)(dst + ((long)n << 7) + (p << 3) + 4) = hi;
  }
}

// 16-row GEMM: Xs[16][128] swizzled bf16  x  Wbuf (pretransposed, swizzled).
// Wave wv covers cols [wv*32, wv*32+32).
__device__ __forceinline__ void gemm16(
    const unsigned short Xs[16][128], const unsigned short* Wbuf,
    int lr, int lk, int wv, f32x4 acc[2])
{
#pragma unroll
  for (int kc = 0; kc < 4; ++kc) {
    int q = (kc << 2) | lk;
    bf16x8 a = *(const bf16x8*)&Xs[lr][(q ^ (lr & 7)) << 3];
#pragma unroll
    for (int nt = 0; nt < 2; ++nt) {
      int n = (wv << 5) | (nt << 4) | lr;
      bf16x8 b = *(const bf16x8*)(Wbuf + n * 128 + ((q ^ (n & 7)) << 3));
      acc[nt] = __builtin_amdgcn_mfma_f32_16x16x32_bf16(a, b, acc[nt], 0, 0, 0);
    }
  }
}

// ---------------- table builder: T_l = ssp(ssp(EA@w1)@w2) * C(d), bf16 ----
// EA computed inline (no global round-trip). grid (TBL_P/16, L).
__global__ __launch_bounds__(256) void k_table(
    const unsigned short* __restrict__ m1t, const float* __restrict__ mlp_b1,
    const unsigned short* __restrict__ m2t, const float* __restrict__ mlp_b2,
    unsigned short* __restrict__ T)
{
  __shared__ unsigned short Xs[16][128];
  __shared__ unsigned short Wbuf[128][128];
  const int l = blockIdx.y;
  const int m0 = blockIdx.x * 16;
  const int tid = threadIdx.x;
  const float step = 10.0f / 49.0f;
  const float coeff = -0.5f / (step * step);

  if (tid < 256) {
    int r = tid >> 4, c = tid & 15;
    float d = (float)(m0 + r) * TBL_DT;
    alignas(16) unsigned short u[8];
#pragma unroll
    for (int k = 0; k < 8; ++k) {
      int g = (c << 3) + k;
      float v = 0.f;
      if (g < NG_GAUSS) { float t2 = d - g * step; v = __expf(coeff * t2 * t2); }
      u[k] = f2bf(v);
    }
    *(int4*)&Xs[r][(c ^ (r & 7)) << 3] = *(int4*)u;
  }
  {
    const int4* s4 = (const int4*)(m1t + (long)l * 16384);
    int4* d4 = (int4*)Wbuf;
    for (int i = tid; i < 2048; i += 256) d4[i] = s4[i];
  }
  __syncthreads();

  const int wv = tid >> 6, lane = tid & 63;
  const int lr = lane & 15, lk = lane >> 4;
  const float* b1 = mlp_b1 + (long)l * 128;
  const float* b2 = mlp_b2 + (long)l * 128;

  f32x4 acc[2];
#pragma unroll
  for (int i = 0; i < 2; ++i)
#pragma unroll
    for (int j = 0; j < 4; ++j) acc[i][j] = 0.f;
  gemm16(Xs, &Wbuf[0][0], lr, lk, wv, acc);
  __syncthreads();
#pragma unroll
  for (int nt = 0; nt < 2; ++nt) {
    int col = (wv << 5) | (nt << 4) | lr;
    float bv = b1[col];
#pragma unroll
    for (int r2 = 0; r2 < 4; ++r2) {
      int row = (lk << 2) | r2;
      float v2 = ssp_f(acc[nt][r2] + bv);
      int cch = col >> 3;
      Xs[row][((cch ^ (row & 7)) << 3) | (col & 7)] = f2bf(v2);
    }
  }
  {
    const int4* s4 = (const int4*)(m2t + (long)l * 16384);
    int4* d4 = (int4*)Wbuf;
    for (int i = tid; i < 2048; i += 256) d4[i] = s4[i];
  }
  __syncthreads();
#pragma unroll
  for (int i = 0; i < 2; ++i)
#pragma unroll
    for (int j = 0; j < 4; ++j) acc[i][j] = 0.f;
  gemm16(Xs, &Wbuf[0][0], lr, lk, wv, acc);

  unsigned short* Tl = T + (long)l * TBL_P * 128;
#pragma unroll
  for (int nt = 0; nt < 2; ++nt) {
    int col = (wv << 5) | (nt << 4) | lr;
    float bv = b2[col];
#pragma unroll
    for (int r2 = 0; r2 < 4; ++r2) {
      int row = (lk << 2) | r2;
      int m = m0 + row;
      float d = (float)m * TBL_DT;
      float v2 = ssp_f(acc[nt][r2] + bv) * 0.5f * (__cosf(d * (PI_F / 10.0f)) + 1.0f);
      Tl[(long)m * 128 + col] = f2bf(v2);
    }
  }
}

// ---------------- init: h0 = emb[z] (bf16), hw0 = h0@aw0 + b0 -------------
__global__ __launch_bounds__(256) void k_init(
    const float* __restrict__ emb, const int* __restrict__ z,
    const unsigned short* __restrict__ W0, const float* __restrict__ b0,
    unsigned short* __restrict__ h, unsigned short* __restrict__ hwout, int N)
{
  __shared__ unsigned short Xs[16][128];
  __shared__ unsigned short Wbuf[128][128];
  const int m0 = blockIdx.x * 16;
  const int tid = threadIdx.x;

  if (tid < 256) {
    int r = tid >> 4, c = tid & 15;
    int m = m0 + r;
    alignas(16) unsigned short u[8] = {0,0,0,0,0,0,0,0};
    if (m < N) {
      const float* er = emb + (long)z[m] * 128 + (c << 3);
      float4 lo = *(const float4*)er;
      float4 hi = *(const float4*)(er + 4);
      u[0]=f2bf(lo.x); u[1]=f2bf(lo.y); u[2]=f2bf(lo.z); u[3]=f2bf(lo.w);
      u[4]=f2bf(hi.x); u[5]=f2bf(hi.y); u[6]=f2bf(hi.z); u[7]=f2bf(hi.w);
      *(int4*)(h + (long)m * 128 + (c << 3)) = *(int4*)u;
    }
    *(int4*)&Xs[r][(c ^ (r & 7)) << 3] = *(int4*)u;
  }
  {
    const int4* s4 = (const int4*)W0;
    int4* d4 = (int4*)Wbuf;
    for (int i = tid; i < 2048; i += 256) d4[i] = s4[i];
  }
  __syncthreads();

  const int wv = tid >> 6, lane = tid & 63;
  const int lr = lane & 15, lk = lane >> 4;
  f32x4 acc[2];
#pragma unroll
  for (int i = 0; i < 2; ++i)
#pragma unroll
    for (int j = 0; j < 4; ++j) acc[i][j] = 0.f;
  gemm16(Xs, &Wbuf[0][0], lr, lk, wv, acc);
#pragma unroll
  for (int nt = 0; nt < 2; ++nt) {
    int col = (wv << 5) | (nt << 4) | lr;
    float bv = b0[col];
#pragma unroll
    for (int r2 = 0; r2 < 4; ++r2) {
      int m = m0 + ((lk << 2) | r2);
      if (m < N) hwout[(long)m * 128 + col] = f2bf(acc[nt][r2] + bv);
    }
  }
}

// ---------------- per-layer: conv (gather) + 3-stage GEMM chain -----------
// conv: wave wv gathers 4 nodes' edges -> Xs tile (swizzled bf16).
// stage A: tmp = ssp(conv@Wa+ba); stage B: h += tmp@Wb+bb (bf16 residual);
// stage C: hwout = h@Wc+bc   OR head: atomicAdd(out[batch], ssp(..)@hw2).
#define CONV_E(PK, AX, AY) {                                                 \
    unsigned pr = (unsigned)(PK);                                            \
    unsigned tv = *(const unsigned*)(T + ((size_t)(pr & 8191u) << 7) + la);  \
    unsigned hv = __builtin_nontemporal_load(                                \
        (const unsigned*)(hwin + ((size_t)(pr >> 13) << 7) + la));           \
    float w0 = __uint_as_float(tv << 16), w1 = __uint_as_float(tv & 0xffff0000u); \
    float h0 = __uint_as_float(hv << 16), h1 = __uint_as_float(hv & 0xffff0000u); \
    AX = fmaf(w0, h0, AX); AY = fmaf(w1, h1, AY); }

__global__ __launch_bounds__(256) void k_layer(
    const int* __restrict__ csr, const int* __restrict__ ptr,
    const unsigned short* __restrict__ T,
    const unsigned short* __restrict__ hwin,
    const unsigned short* __restrict__ Wa, const float* __restrict__ ba,
    const unsigned short* __restrict__ Wb, const float* __restrict__ bb,
    unsigned short* __restrict__ h,
    const unsigned short* __restrict__ Wc, const float* __restrict__ bc,
    unsigned short* __restrict__ hwout,
    const float* __restrict__ hw2, const float* __restrict__ hb2,
    const int* __restrict__ batchp, float* __restrict__ outp,
    int N)
{
  __shared__ unsigned short Xs[16][128];
  __shared__ unsigned short Wbuf[128][128];
  const int m0 = blockIdx.x * 16;
  const int tid = threadIdx.x;
  const int wv = tid >> 6, lane = tid & 63;
  const int la = lane << 1;

  // ---- conv phase: wave wv handles rows [wv*4, wv*4+4) ----
#pragma unroll
  for (int ni = 0; ni < 4; ++ni) {
    int row = (wv << 2) + ni;
    int node = m0 + row;
    float ax0=0.f, ay0=0.f, ax1=0.f, ay1=0.f;
    float ax2=0.f, ay2=0.f, ax3=0.f, ay3=0.f;
    if (node < N) {
      int s = __builtin_amdgcn_readfirstlane(ptr[node]);
      int e = __builtin_amdgcn_readfirstlane(ptr[node + 1]);
      int j = s;
      for (; j + 4 <= e; j += 4) {
        int c0 = csr[j], c1 = csr[j+1], c2 = csr[j+2], c3 = csr[j+3];
        CONV_E(c0, ax0, ay0);
        CONV_E(c1, ax1, ay1);
        CONV_E(c2, ax2, ay2);
        CONV_E(c3, ax3, ay3);
      }
      for (; j < e; ++j) { int c0 = csr[j]; CONV_E(c0, ax0, ay0); }
    }
    float axs = (ax0 + ax1) + (ax2 + ax3);
    float ays = (ay0 + ay1) + (ay2 + ay3);
    int ch = la >> 3;
    unsigned ow = (unsigned)f2bf(axs) | ((unsigned)f2bf(ays) << 16);
    *(unsigned*)&Xs[row][((ch ^ (row & 7)) << 3) | (la & 7)] = ow;
  }
  {
    const int4* s4 = (const int4*)Wa;
    int4* d4 = (int4*)Wbuf;
    for (int i = tid; i < 2048; i += 256) d4[i] = s4[i];
  }
  __syncthreads();

  const int lr = lane & 15, lk = lane >> 4;
  f32x4 acc[2];

  // ---- stage A: tmp = ssp(conv@Wa + ba) -> Xs ----
#pragma unroll
  for (int i = 0; i < 2; ++i)
#pragma unroll
    for (int j = 0; j < 4; ++j) acc[i][j] = 0.f;
  gemm16(Xs, &Wbuf[0][0], lr, lk, wv, acc);
  __syncthreads();
#pragma unroll
  for (int nt = 0; nt < 2; ++nt) {
    int col = (wv << 5) | (nt << 4) | lr;
    float bv = ba[col];
#pragma unroll
    for (int r2 = 0; r2 < 4; ++r2) {
      int row = (lk << 2) | r2;
      float v2 = ssp_f(acc[nt][r2] + bv);
      int cch = col >> 3;
      Xs[row][((cch ^ (row & 7)) << 3) | (col & 7)] = f2bf(v2);
    }
  }
  {
    const int4* s4 = (const int4*)Wb;
    int4* d4 = (int4*)Wbuf;
    for (int i = tid; i < 2048; i += 256) d4[i] = s4[i];
  }
  __syncthreads();

  // ---- stage B: v = tmp@Wb + bb + h; h = v (bf16); Xs = v ----
#pragma unroll
  for (int i = 0; i < 2; ++i)
#pragma unroll
    for (int j = 0; j < 4; ++j) acc[i][j] = 0.f;
  gemm16(Xs, &Wbuf[0][0], lr, lk, wv, acc);
  __syncthreads();
#pragma unroll
  for (int nt = 0; nt < 2; ++nt) {
    int col = (wv << 5) | (nt << 4) | lr;
    float bv = bb[col];
#pragma unroll
    for (int r2 = 0; r2 < 4; ++r2) {
      int row = (lk << 2) | r2;
      int m = m0 + row;
      float v2 = acc[nt][r2] + bv;
      if (m < N) {
        v2 += bf2f_s(h[(long)m * 128 + col]);
        h[(long)m * 128 + col] = f2bf(v2);
      }
      int cch = col >> 3;
      Xs[row][((cch ^ (row & 7)) << 3) | (col & 7)] = f2bf(v2);
    }
  }
  {
    const int4* s4 = (const int4*)Wc;
    int4* d4 = (int4*)Wbuf;
    for (int i = tid; i < 2048; i += 256) d4[i] = s4[i];
  }
  __syncthreads();

  // ---- stage C: next-layer hw, or fused head ----
#pragma unroll
  for (int i = 0; i < 2; ++i)
#pragma unroll
    for (int j = 0; j < 4; ++j) acc[i][j] = 0.f;
  gemm16(Xs, &Wbuf[0][0], lr, lk, wv, acc);

  if (hw2) {
    // head cols 0..63 live in waves 0,1; each contributes a 32-col partial.
    if (wv < 2) {
      float b1v[2], w2v[2];
#pragma unroll
      for (int nt = 0; nt < 2; ++nt) {
        int col = (wv << 5) | (nt << 4) | lr;
        b1v[nt] = bc[col];
        w2v[nt] = hw2[col];
      }
      float bias2 = (wv == 0) ? hb2[0] : 0.f;
#pragma unroll
      for (int r2 = 0; r2 < 4; ++r2) {
        float sv = 0.f;
#pragma unroll
        for (int nt = 0; nt < 2; ++nt)
          sv += ssp_f(acc[nt][r2] + b1v[nt]) * w2v[nt];
        sv += __shfl_xor(sv, 1);
        sv += __shfl_xor(sv, 2);
        sv += __shfl_xor(sv, 4);
        sv += __shfl_xor(sv, 8);
        if (lr == 0) {
          int m = m0 + ((lk << 2) | r2);
          if (m < N) atomicAdd(&outp[batchp[m]], sv + bias2);
        }
      }
    }
  } else {
#pragma unroll
    for (int nt = 0; nt < 2; ++nt) {
      int col = (wv << 5) | (nt << 4) | lr;
      float bv = bc[col];
#pragma unroll
      for (int r2 = 0; r2 < 4; ++r2) {
        int m = m0 + ((lk << 2) | r2);
        if (m < N) hwout[(long)m * 128 + col] = f2bf(acc[nt][r2] + bv);
      }
    }
  }
}

extern "C" void kernel_launch(void* const* d_in, const int* in_sizes, int n_in,
                              void* d_out, int out_size, void* d_ws, size_t ws_size,
                              hipStream_t stream) {
  (void)n_in; (void)ws_size;
  const float* pos     = (const float*)d_in[0];
  const int*   z       = (const int*)d_in[1];
  const int*   batch   = (const int*)d_in[2];
  const int*   ei      = (const int*)d_in[3];
  const float* emb     = (const float*)d_in[4];
  const float* mlp_w1  = (const float*)d_in[5];
  const float* mlp_b1  = (const float*)d_in[6];
  const float* mlp_w2  = (const float*)d_in[7];
  const float* mlp_b2  = (const float*)d_in[8];
  const float* aw_w    = (const float*)d_in[9];
  const float* aw_b    = (const float*)d_in[10];
  const float* out_w1  = (const float*)d_in[11];
  const float* out_b1  = (const float*)d_in[12];
  const float* out_w2  = (const float*)d_in[13];
  const float* out_b2  = (const float*)d_in[14];
  const float* head_w1 = (const float*)d_in[15];
  const float* head_b1 = (const float*)d_in[16];
  const float* head_w2 = (const float*)d_in[17];
  const float* head_b2 = (const float*)d_in[18];

  const int N  = in_sizes[0] / 3;
  const int E  = in_sizes[3] / 2;
  const int NG = out_size;
  const int L  = in_sizes[5] / (NG_GAUSS * HID);

  char* ws = (char*)d_ws;
  size_t off = 0;
  auto alloc = [&](size_t bytes) -> void* {
    off = (off + 255) & ~(size_t)255;
    void* p = ws + off;
    off += bytes;
    return p;
  };

  const size_t nh2 = (size_t)N * HID * 2;  // bf16 [N][128]
  unsigned short* h = (unsigned short*)alloc(nh2 > (size_t)E * 4 ? nh2 : (size_t)E * 4);
  int* epack = (int*)h;                     // alias (disjoint lifetime)
  unsigned short* hwA = (unsigned short*)alloc(nh2);
  unsigned short* hwB = (unsigned short*)alloc(nh2);
  int* csr = (int*)alloc((size_t)E * 4);
  unsigned short* T   = (unsigned short*)alloc((size_t)L * TBL_P * 128 * 2);
  unsigned short* awt = (unsigned short*)alloc((size_t)L * 16384 * 2);
  unsigned short* o1t = (unsigned short*)alloc((size_t)L * 16384 * 2);
  unsigned short* o2t = (unsigned short*)alloc((size_t)L * 16384 * 2);
  unsigned short* m2t = (unsigned short*)alloc((size_t)L * 16384 * 2);
  unsigned short* m1t = (unsigned short*)alloc((size_t)L * 16384 * 2);
  unsigned short* hwt = (unsigned short*)alloc((size_t)16384 * 2);
  int* deg    = (int*)alloc((size_t)N * 4);
  int* ptr    = (int*)alloc((size_t)(N + 1) * 4);
  int* cursor = (int*)alloc((size_t)N * 4);

  hipMemsetAsync(deg, 0, (size_t)N * 4, stream);
  hipMemsetAsync(cursor, 0, (size_t)N * 4, stream);
  hipMemsetAsync(d_out, 0, (size_t)NG * 4, stream);

  int egrid = (E + 255) / 256;
  k_edge_pre<<<egrid, 256, 0, stream>>>(pos, ei, E, epack, deg);
  k_scan<<<1, 1024, 0, stream>>>(deg, ptr, N);
  k_csr_scatter<<<egrid, 256, 0, stream>>>(ei + E, epack, ptr, cursor, csr, E);

  k_wprep<<<dim3(L, 6, 2), 256, 0, stream>>>(aw_w, out_w1, out_w2, mlp_w2,
                                             mlp_w1, head_w1,
                                             awt, o1t, o2t, m2t, m1t, hwt);
  k_table<<<dim3(TBL_P / 16, L), 256, 0, stream>>>(m1t, mlp_b1, m2t, mlp_b2, T);

  const int ngrid = (N + 15) / 16;
  k_init<<<ngrid, 256, 0, stream>>>(emb, z, awt, aw_b, h, hwA, N);

  unsigned short* hin = hwA;
  unsigned short* hout = hwB;
  for (int l = 0; l < L; ++l) {
    const int last = (l + 1 == L);
    k_layer<<<ngrid, 256, 0, stream>>>(
        csr, ptr, T + (size_t)l * TBL_P * 128, hin,
        o1t + (size_t)l * 16384, out_b1 + (size_t)l * 128,
        o2t + (size_t)l * 16384, out_b2 + (size_t)l * 128,
        h,
        last ? hwt : (awt + (size_t)(l + 1) * 16384),
        last ? head_b1 : (aw_b + (size_t)(l + 1) * 128),
        last ? (unsigned short*)0 : hout,
        last ? head_w2 : (const float*)0,
        last ? head_b2 : (const float*)0,
        last ? batch : (const int*)0,
        last ? (float*)d_out : (float*)0,
        N);
    unsigned short* t2 = hin; hin = hout; hout = t2;
  }
}